// Round 1
// baseline (688.100 us; speedup 1.0000x reference)
//
#include <hip/hip_runtime.h>
#include <hip/hip_fp16.h>
#include <cstdint>

// Shapes (all compile-time constants for this problem)
#define M_TOK 8192
#define K_IN  4096
#define N_OUT 4096
#define RANK  64

typedef _Float16 f16x8 __attribute__((ext_vector_type(8)));
typedef _Float16 f16x4 __attribute__((ext_vector_type(4)));
typedef float    f32x4 __attribute__((ext_vector_type(4)));

// ---------------------------------------------------------------------------
// async global->LDS, 16B per lane.  LDS dest is wave-uniform base + lane*16.
// ---------------------------------------------------------------------------
__device__ __forceinline__ void gld_lds16(const void* g, void* l) {
    __builtin_amdgcn_global_load_lds(
        (const __attribute__((address_space(1))) void*)g,
        (__attribute__((address_space(3))) void*)l,
        16, 0, 0);
}

// ---------------------------------------------------------------------------
// Conversion kernels
// ---------------------------------------------------------------------------
__global__ void k_cvt_f32_f16(const float4* __restrict__ in,
                              f16x4* __restrict__ out, int n4) {
    int i = blockIdx.x * 256 + threadIdx.x;
    if (i >= n4) return;
    float4 v = in[i];
    f16x4 r;
    r[0] = (_Float16)v.x; r[1] = (_Float16)v.y;
    r[2] = (_Float16)v.z; r[3] = (_Float16)v.w;
    out[i] = r;
}

// W_f16[o][k] = f16(Q[o][k] * scales[o]).  4 elems/thread, same row (4096%4==0).
__global__ void k_cvt_w(const int4* __restrict__ Q, const float* __restrict__ s,
                        f16x4* __restrict__ W) {
    int i = blockIdx.x * 256 + threadIdx.x;      // group-of-4 index, < 4194304
    float sc = s[i >> 10];                       // (i*4)/4096
    int4 q = Q[i];
    f16x4 r;
    r[0] = (_Float16)(q.x * sc); r[1] = (_Float16)(q.y * sc);
    r[2] = (_Float16)(q.z * sc); r[3] = (_Float16)(q.w * sc);
    W[i] = r;
}

// ---------------------------------------------------------------------------
// t = x_f16 @ D_f16.T  -> [8192][64] f16.   Block: 256 thr (4 waves), 64 rows.
// ---------------------------------------------------------------------------
__global__ __launch_bounds__(256)
void k_t(const _Float16* __restrict__ X, const _Float16* __restrict__ Dh,
         _Float16* __restrict__ T) {
    __shared__ _Float16 Xs[64 * 32];
    __shared__ _Float16 Ds[64 * 32];
    const int tid = threadIdx.x, wave = tid >> 6, lane = tid & 63;
    const int blk = blockIdx.x;
    const int rr = lane >> 2, c8 = (lane & 3) * 8;
    const int fm = lane & 15, fk = (lane >> 4) * 8;
    f32x4 acc[4] = {};

    for (int k0 = 0; k0 < K_IN; k0 += 32) {
        gld_lds16(X + (size_t)(blk * 64 + wave * 16 + rr) * K_IN + k0 + c8,
                  Xs + wave * 16 * 32);
        gld_lds16(Dh + (size_t)(wave * 16 + rr) * K_IN + k0 + c8,
                  Ds + wave * 16 * 32);
        __syncthreads();
        f16x8 a = *(const f16x8*)&Xs[(wave * 16 + fm) * 32 + fk];
#pragma unroll
        for (int n = 0; n < 4; n++) {
            f16x8 b = *(const f16x8*)&Ds[(n * 16 + fm) * 32 + fk];
            acc[n] = __builtin_amdgcn_mfma_f32_16x16x32_f16(a, b, acc[n], 0, 0, 0);
        }
        __syncthreads();
    }
#pragma unroll
    for (int n = 0; n < 4; n++)
#pragma unroll
        for (int r = 0; r < 4; r++) {
            int row = blk * 64 + wave * 16 + (lane >> 4) * 4 + r;
            int col = n * 16 + (lane & 15);
            T[(size_t)row * RANK + col] = (_Float16)acc[n][r];
        }
}

// ---------------------------------------------------------------------------
// Main GEMM: C[n][o] = sum_k A[n,k]*B[o,k]  (+ fused adapter K-steps).
// 128x128 tile, BK=32, 4 waves each computing 64x64 via 4x4 of 16x16x32 MFMA.
// m97 ladder structure: global_load_lds width=16, unpadded LDS.
// ---------------------------------------------------------------------------
__global__ __launch_bounds__(256)
void k_main(const _Float16* __restrict__ A,   // [8192][4096] x_f16
            const _Float16* __restrict__ B,   // [4096][4096] W_f16 (pre-scaled)
            const _Float16* __restrict__ T,   // [8192][64]   t_f16
            const _Float16* __restrict__ U,   // [4096][64]   U_f16
            float* __restrict__ C) {          // [8192][4096]
    __shared__ _Float16 As[128 * 32];
    __shared__ _Float16 Bs[128 * 32];
    const int tid = threadIdx.x, wave = tid >> 6, lane = tid & 63;
    const int bx = blockIdx.x, by = blockIdx.y;
    const int wr = wave >> 1, wc = wave & 1;
    const int rr = lane >> 2, c8 = (lane & 3) * 8;
    const int fm = lane & 15, fk = (lane >> 4) * 8;
    const int arow0 = by * 128, brow0 = bx * 128;

    f32x4 acc[4][4] = {};

    auto step = [&](const _Float16* Ab, size_t lda,
                    const _Float16* Bb, size_t ldb, int k0) {
        // stage A tile: wave w covers rows [w*32, w*32+32), two 16-row issues
        const _Float16* ga = Ab + (size_t)(arow0 + wave * 32 + rr) * lda + k0 + c8;
        gld_lds16(ga,            As + wave * 32 * 32);
        gld_lds16(ga + 16 * lda, As + wave * 32 * 32 + 16 * 32);
        const _Float16* gb = Bb + (size_t)(brow0 + wave * 32 + rr) * ldb + k0 + c8;
        gld_lds16(gb,            Bs + wave * 32 * 32);
        gld_lds16(gb + 16 * ldb, Bs + wave * 32 * 32 + 16 * 32);
        __syncthreads();
        f16x8 a[4], b[4];
#pragma unroll
        for (int m = 0; m < 4; m++)
            a[m] = *(const f16x8*)&As[(wr * 64 + m * 16 + fm) * 32 + fk];
#pragma unroll
        for (int n = 0; n < 4; n++)
            b[n] = *(const f16x8*)&Bs[(wc * 64 + n * 16 + fm) * 32 + fk];
#pragma unroll
        for (int m = 0; m < 4; m++)
#pragma unroll
            for (int n = 0; n < 4; n++)
                acc[m][n] = __builtin_amdgcn_mfma_f32_16x16x32_f16(
                    a[m], b[n], acc[m][n], 0, 0, 0);
        __syncthreads();
    };

    for (int k0 = 0; k0 < K_IN; k0 += 32)
        step(A, K_IN, B, K_IN, k0);
    // fused low-rank adapter: 2 more K-steps from T (A-side) and U (B-side)
    step(T, RANK, U, RANK, 0);
    step(T, RANK, U, RANK, 32);

    // epilogue: C/D layout col=lane&15, row=(lane>>4)*4+reg  [m89/m91 verified]
#pragma unroll
    for (int m = 0; m < 4; m++) {
        int row = by * 128 + wr * 64 + m * 16 + (lane >> 4) * 4;
#pragma unroll
        for (int n = 0; n < 4; n++) {
            int col = bx * 128 + wc * 64 + n * 16 + (lane & 15);
            float* cp = C + (size_t)row * N_OUT + col;
#pragma unroll
            for (int r = 0; r < 4; r++)
                cp[(size_t)r * N_OUT] = acc[m][n][r];
        }
    }
}

// ---------------------------------------------------------------------------
// Fallback (only if workspace is too small): naive fp32, correct but slow.
// ---------------------------------------------------------------------------
__global__ void fb_t(const float* __restrict__ x, const float* __restrict__ Dm,
                     float* __restrict__ t) {
    int n = blockIdx.x, r = threadIdx.x;   // 8192 blocks x 64 threads
    const float* xr = x + (size_t)n * K_IN;
    const float* dr = Dm + (size_t)r * K_IN;
    float s = 0.f;
    for (int k = 0; k < K_IN; k++) s += xr[k] * dr[k];
    t[n * RANK + r] = s;
}

__global__ void fb_main(const float* __restrict__ x, const float* __restrict__ scales,
                        const float* __restrict__ U, const int* __restrict__ Q,
                        const float* __restrict__ t, float* __restrict__ out) {
    size_t i = (size_t)blockIdx.x * 256 + threadIdx.x;
    int n = (int)(i >> 12), o = (int)(i & 4095);
    const float* xr = x + (size_t)n * K_IN;
    const int* qr = Q + (size_t)o * K_IN;
    float s = 0.f;
    for (int k = 0; k < K_IN; k++) s += xr[k] * (float)qr[k];
    float a = 0.f;
    const float* tr = t + (size_t)n * RANK;
    const float* ur = U + (size_t)o * RANK;
    for (int r = 0; r < RANK; r++) a += tr[r] * ur[r];
    out[i] = scales[o] * s + a;
}

// ---------------------------------------------------------------------------
extern "C" void kernel_launch(void* const* d_in, const int* in_sizes, int n_in,
                              void* d_out, int out_size, void* d_ws, size_t ws_size,
                              hipStream_t stream) {
    const float* x      = (const float*)d_in[0];   // [8192][4096]
    const float* scales = (const float*)d_in[1];   // [4096]
    const float* U      = (const float*)d_in[2];   // [4096][64]
    const float* D      = (const float*)d_in[3];   // [64][4096]
    const int*   Q      = (const int*)d_in[4];     // [4096][4096]
    float* out = (float*)d_out;

    const size_t SZ_X = (size_t)M_TOK * K_IN * 2;   // 67,108,864
    const size_t SZ_W = (size_t)N_OUT * K_IN * 2;   // 33,554,432
    const size_t SZ_U = (size_t)N_OUT * RANK * 2;   //    524,288
    const size_t SZ_D = (size_t)RANK * K_IN * 2;    //    524,288
    const size_t SZ_T = (size_t)M_TOK * RANK * 2;   //  1,048,576
    const size_t NEED = SZ_X + SZ_W + SZ_U + SZ_D + SZ_T;

    if (ws_size >= NEED) {
        char* w = (char*)d_ws;
        _Float16* xh = (_Float16*)w;                       w += SZ_X;
        _Float16* Wh = (_Float16*)w;                       w += SZ_W;
        _Float16* Uh = (_Float16*)w;                       w += SZ_U;
        _Float16* Dh = (_Float16*)w;                       w += SZ_D;
        _Float16* Th = (_Float16*)w;

        k_cvt_f32_f16<<<32768, 256, 0, stream>>>((const float4*)x, (f16x4*)xh,
                                                 M_TOK * K_IN / 4);
        k_cvt_w<<<16384, 256, 0, stream>>>((const int4*)Q, scales, (f16x4*)Wh);
        k_cvt_f32_f16<<<256, 256, 0, stream>>>((const float4*)U, (f16x4*)Uh,
                                               N_OUT * RANK / 4);
        k_cvt_f32_f16<<<256, 256, 0, stream>>>((const float4*)D, (f16x4*)Dh,
                                               RANK * K_IN / 4);
        k_t<<<M_TOK / 64, 256, 0, stream>>>(xh, Dh, Th);
        k_main<<<dim3(N_OUT / 128, M_TOK / 128), 256, 0, stream>>>(xh, Wh, Th, Uh, out);
    } else {
        // slow-but-correct fallback (needs only 2 MB for t)
        float* t32 = (float*)d_ws;
        fb_t<<<M_TOK, RANK, 0, stream>>>(x, D, t32);
        fb_main<<<(int)((size_t)M_TOK * N_OUT / 256), 256, 0, stream>>>(
            x, scales, U, Q, t32, out);
    }
}

// Round 2
// 642.835 us; speedup vs baseline: 1.0704x; 1.0704x over previous
//
#include <hip/hip_runtime.h>
#include <hip/hip_fp16.h>
#include <cstdint>

#define M_TOK 8192
#define K_IN  4096
#define N_OUT 4096
#define RANK  64
#define KSPLIT 8          // k_t split-K factor; chunk = K_IN/KSPLIT = 512

typedef _Float16 f16x8 __attribute__((ext_vector_type(8)));
typedef _Float16 f16x4 __attribute__((ext_vector_type(4)));
typedef float    f32x4 __attribute__((ext_vector_type(4)));

__device__ __forceinline__ void gld_lds16(const void* g, void* l) {
    __builtin_amdgcn_global_load_lds(
        (const __attribute__((address_space(1))) void*)g,
        (__attribute__((address_space(3))) void*)l,
        16, 0, 0);
}

// ---------------------------------------------------------------------------
// Conversion kernels
// ---------------------------------------------------------------------------
__global__ void k_cvt_f32_f16(const float4* __restrict__ in,
                              f16x4* __restrict__ out, int n4) {
    int i = blockIdx.x * 256 + threadIdx.x;
    if (i >= n4) return;
    float4 v = in[i];
    f16x4 r;
    r[0] = (_Float16)v.x; r[1] = (_Float16)v.y;
    r[2] = (_Float16)v.z; r[3] = (_Float16)v.w;
    out[i] = r;
}

// W_f16[o][k] = f16(Q[o][k]*scales[o]).  8 elems/thread, 16B stores.
__global__ void k_cvt_w8(const int4* __restrict__ Q, const float* __restrict__ s,
                         f16x8* __restrict__ W) {
    int i = blockIdx.x * 256 + threadIdx.x;   // group-of-8 index, < 2097152
    float sc = s[i >> 9];                     // (i*8)/4096
    int4 q0 = Q[2 * i], q1 = Q[2 * i + 1];
    f16x8 r;
    r[0] = (_Float16)(q0.x * sc); r[1] = (_Float16)(q0.y * sc);
    r[2] = (_Float16)(q0.z * sc); r[3] = (_Float16)(q0.w * sc);
    r[4] = (_Float16)(q1.x * sc); r[5] = (_Float16)(q1.y * sc);
    r[6] = (_Float16)(q1.z * sc); r[7] = (_Float16)(q1.w * sc);
    W[i] = r;
}

// ---------------------------------------------------------------------------
// Fused: x fp32 -> xh f16 (full write-out)  +  partial t = x @ D.T (split-K).
// Grid: (128 row-blocks, 8 k-chunks) = 1024 blocks, 256 thr.
// Each block owns a private [64 x 512] chunk of x: reads fp32, converts in
// registers, writes xh, stages to LDS, MFMAs vs Dh. Partial f32 to T32[kc].
// ---------------------------------------------------------------------------
__global__ __launch_bounds__(256)
void k_t_fused(const float* __restrict__ X, const _Float16* __restrict__ Dh,
               _Float16* __restrict__ Xh, float* __restrict__ T32) {
    __shared__ _Float16 Xs[64 * 32];
    __shared__ _Float16 Ds[64 * 32];
    const int tid = threadIdx.x, wave = tid >> 6, lane = tid & 63;
    const int row0 = blockIdx.x * 64;
    const int kbase = blockIdx.y * (K_IN / KSPLIT);
    const int lr = tid >> 2, lk = (tid & 3) * 8;     // x-load: row, k-offset
    const int rr = lane >> 2, c8 = (lane & 3) * 8;   // gld_lds lane mapping
    const int fm = lane & 15, fk = (lane >> 4) * 8;  // MFMA fragment mapping
    f32x4 acc[4] = {};

    for (int kk = 0; kk < K_IN / KSPLIT; kk += 32) {
        const int k0 = kbase + kk;
        // x: global fp32 -> regs -> convert -> xh global + Xs LDS
        const float* gx = X + (size_t)(row0 + lr) * K_IN + k0 + lk;
        float4 v0 = *(const float4*)gx;
        float4 v1 = *(const float4*)(gx + 4);
        f16x8 h;
        h[0] = (_Float16)v0.x; h[1] = (_Float16)v0.y;
        h[2] = (_Float16)v0.z; h[3] = (_Float16)v0.w;
        h[4] = (_Float16)v1.x; h[5] = (_Float16)v1.y;
        h[6] = (_Float16)v1.z; h[7] = (_Float16)v1.w;
        *(f16x8*)(Xh + (size_t)(row0 + lr) * K_IN + k0 + lk) = h;
        *(f16x8*)&Xs[lr * 32 + lk] = h;
        // D: async stage, wave w covers rank-rows [w*16, w*16+16)
        gld_lds16(Dh + (size_t)(wave * 16 + rr) * K_IN + k0 + c8,
                  Ds + wave * 16 * 32);
        __syncthreads();
        f16x8 a = *(const f16x8*)&Xs[(wave * 16 + fm) * 32 + fk];
#pragma unroll
        for (int n = 0; n < 4; n++) {
            f16x8 b = *(const f16x8*)&Ds[(n * 16 + fm) * 32 + fk];
            acc[n] = __builtin_amdgcn_mfma_f32_16x16x32_f16(a, b, acc[n], 0, 0, 0);
        }
        __syncthreads();
    }
    // partial out: T32[kc][row][col]
#pragma unroll
    for (int n = 0; n < 4; n++)
#pragma unroll
        for (int r = 0; r < 4; r++) {
            int row = row0 + wave * 16 + (lane >> 4) * 4 + r;
            int col = n * 16 + (lane & 15);
            T32[((size_t)blockIdx.y * M_TOK + row) * RANK + col] = acc[n][r];
        }
}

// Th[i] = f16( sum_c T32[c][i] ),  i < 8192*64
__global__ void k_reduce_t(const float* __restrict__ T32,
                           _Float16* __restrict__ Th) {
    int i = blockIdx.x * 256 + threadIdx.x;
    float s = 0.f;
#pragma unroll
    for (int c = 0; c < KSPLIT; c++)
        s += T32[(size_t)c * M_TOK * RANK + i];
    Th[i] = (_Float16)s;
}

// ---------------------------------------------------------------------------
// Main GEMM (unchanged from R1 — at the m97-structure plateau, 379 us):
// 128x128 tile, BK=32, 4 waves x (64x64 via 4x4 MFMA 16x16x32), fused adapter.
// ---------------------------------------------------------------------------
__global__ __launch_bounds__(256)
void k_main(const _Float16* __restrict__ A, const _Float16* __restrict__ B,
            const _Float16* __restrict__ T, const _Float16* __restrict__ U,
            float* __restrict__ C) {
    __shared__ _Float16 As[128 * 32];
    __shared__ _Float16 Bs[128 * 32];
    const int tid = threadIdx.x, wave = tid >> 6, lane = tid & 63;
    const int bx = blockIdx.x, by = blockIdx.y;
    const int wr = wave >> 1, wc = wave & 1;
    const int rr = lane >> 2, c8 = (lane & 3) * 8;
    const int fm = lane & 15, fk = (lane >> 4) * 8;
    const int arow0 = by * 128, brow0 = bx * 128;

    f32x4 acc[4][4] = {};

    auto step = [&](const _Float16* Ab, size_t lda,
                    const _Float16* Bb, size_t ldb, int k0) {
        const _Float16* ga = Ab + (size_t)(arow0 + wave * 32 + rr) * lda + k0 + c8;
        gld_lds16(ga,            As + wave * 32 * 32);
        gld_lds16(ga + 16 * lda, As + wave * 32 * 32 + 16 * 32);
        const _Float16* gb = Bb + (size_t)(brow0 + wave * 32 + rr) * ldb + k0 + c8;
        gld_lds16(gb,            Bs + wave * 32 * 32);
        gld_lds16(gb + 16 * ldb, Bs + wave * 32 * 32 + 16 * 32);
        __syncthreads();
        f16x8 a[4], b[4];
#pragma unroll
        for (int m = 0; m < 4; m++)
            a[m] = *(const f16x8*)&As[(wr * 64 + m * 16 + fm) * 32 + fk];
#pragma unroll
        for (int n = 0; n < 4; n++)
            b[n] = *(const f16x8*)&Bs[(wc * 64 + n * 16 + fm) * 32 + fk];
#pragma unroll
        for (int m = 0; m < 4; m++)
#pragma unroll
            for (int n = 0; n < 4; n++)
                acc[m][n] = __builtin_amdgcn_mfma_f32_16x16x32_f16(
                    a[m], b[n], acc[m][n], 0, 0, 0);
        __syncthreads();
    };

    for (int k0 = 0; k0 < K_IN; k0 += 32)
        step(A, K_IN, B, K_IN, k0);
    step(T, RANK, U, RANK, 0);
    step(T, RANK, U, RANK, 32);

#pragma unroll
    for (int m = 0; m < 4; m++) {
        int row = by * 128 + wr * 64 + m * 16 + (lane >> 4) * 4;
#pragma unroll
        for (int n = 0; n < 4; n++) {
            int col = bx * 128 + wc * 64 + n * 16 + (lane & 15);
            float* cp = C + (size_t)row * N_OUT + col;
#pragma unroll
            for (int r = 0; r < 4; r++)
                cp[(size_t)r * N_OUT] = acc[m][n][r];
        }
    }
}

// ---------------------------------------------------------------------------
// Naive fp32 fallback (ws too small)
// ---------------------------------------------------------------------------
__global__ void fb_t(const float* __restrict__ x, const float* __restrict__ Dm,
                     float* __restrict__ t) {
    int n = blockIdx.x, r = threadIdx.x;
    const float* xr = x + (size_t)n * K_IN;
    const float* dr = Dm + (size_t)r * K_IN;
    float s = 0.f;
    for (int k = 0; k < K_IN; k++) s += xr[k] * dr[k];
    t[n * RANK + r] = s;
}

__global__ void fb_main(const float* __restrict__ x, const float* __restrict__ scales,
                        const float* __restrict__ U, const int* __restrict__ Q,
                        const float* __restrict__ t, float* __restrict__ out) {
    size_t i = (size_t)blockIdx.x * 256 + threadIdx.x;
    int n = (int)(i >> 12), o = (int)(i & 4095);
    const float* xr = x + (size_t)n * K_IN;
    const int* qr = Q + (size_t)o * K_IN;
    float s = 0.f;
    for (int k = 0; k < K_IN; k++) s += xr[k] * (float)qr[k];
    float a = 0.f;
    const float* tr = t + (size_t)n * RANK;
    const float* ur = U + (size_t)o * RANK;
    for (int r = 0; r < RANK; r++) a += tr[r] * ur[r];
    out[i] = scales[o] * s + a;
}

// ---------------------------------------------------------------------------
extern "C" void kernel_launch(void* const* d_in, const int* in_sizes, int n_in,
                              void* d_out, int out_size, void* d_ws, size_t ws_size,
                              hipStream_t stream) {
    const float* x      = (const float*)d_in[0];
    const float* scales = (const float*)d_in[1];
    const float* U      = (const float*)d_in[2];
    const float* D      = (const float*)d_in[3];
    const int*   Q      = (const int*)d_in[4];
    float* out = (float*)d_out;

    const size_t SZ_X   = (size_t)M_TOK * K_IN * 2;
    const size_t SZ_W   = (size_t)N_OUT * K_IN * 2;
    const size_t SZ_U   = (size_t)N_OUT * RANK * 2;
    const size_t SZ_D   = (size_t)RANK * K_IN * 2;
    const size_t SZ_T   = (size_t)M_TOK * RANK * 2;
    const size_t SZ_T32 = (size_t)KSPLIT * M_TOK * RANK * 4;
    const size_t NEED   = SZ_X + SZ_W + SZ_U + SZ_D + SZ_T + SZ_T32;

    if (ws_size >= NEED) {
        char* w = (char*)d_ws;
        _Float16* xh  = (_Float16*)w; w += SZ_X;
        _Float16* Wh  = (_Float16*)w; w += SZ_W;
        _Float16* Uh  = (_Float16*)w; w += SZ_U;
        _Float16* Dh  = (_Float16*)w; w += SZ_D;
        _Float16* Th  = (_Float16*)w; w += SZ_T;
        float*    T32 = (float*)w;

        k_cvt_f32_f16<<<256, 256, 0, stream>>>((const float4*)U, (f16x4*)Uh,
                                               N_OUT * RANK / 4);
        k_cvt_f32_f16<<<256, 256, 0, stream>>>((const float4*)D, (f16x4*)Dh,
                                               RANK * K_IN / 4);
        k_t_fused<<<dim3(M_TOK / 64, KSPLIT), 256, 0, stream>>>(x, Dh, xh, T32);
        k_reduce_t<<<M_TOK * RANK / 256, 256, 0, stream>>>(T32, Th);
        k_cvt_w8<<<N_OUT * K_IN / 8 / 256, 256, 0, stream>>>((const int4*)Q,
                                                             scales, (f16x8*)Wh);
        k_main<<<dim3(N_OUT / 128, M_TOK / 128), 256, 0, stream>>>(xh, Wh, Th, Uh, out);
    } else {
        float* t32 = (float*)d_ws;
        fb_t<<<M_TOK, RANK, 0, stream>>>(x, D, t32);
        fb_main<<<(int)((size_t)M_TOK * N_OUT / 256), 256, 0, stream>>>(
            x, scales, U, Q, t32, out);
    }
}